// Round 11
// baseline (141.679 us; speedup 1.0000x reference)
//
#include <hip/hip_runtime.h>

// CINLayer: cin_out[b,f,d] = sum_{c,n} W[f,c,n] * xj[b,c,d] * x0[b,n,d]
//           cin_p_out[b,f] = sum_d cin_out[b,f,d]
// B=2048, C=64, N=64, D=64, F=128.
//
// R11 = R7 (best, 139.7us) + VALU surgery:
//  - A' = af * xj via inline-asm v_pk_mul_f16 (4 insts/fragment, guaranteed)
//  - xj staged in LDS as pre-duplicated u32 pairs ((h<<16)|h): ds_read_b32
//    gives broadcast-ready half2 operands, zero per-phase pack/cvt VALU.
// Everything else identical to R7.

typedef _Float16 f16;
typedef __attribute__((ext_vector_type(8))) _Float16 half8;
typedef __attribute__((ext_vector_type(16))) float f32x16;
typedef __attribute__((ext_vector_type(4))) float f32x4;

#define MFMA(a, b, c) __builtin_amdgcn_mfma_f32_32x32x16_f16(a, b, c, 0, 0, 0)

union U8 { half8 v; unsigned u[4]; };

__device__ __forceinline__ half8 scale8a(half8 a, unsigned hdup) {
  U8 in, out;
  in.v = a;
  asm("v_pk_mul_f16 %0, %1, %2" : "=v"(out.u[0]) : "v"(in.u[0]), "v"(hdup));
  asm("v_pk_mul_f16 %0, %1, %2" : "=v"(out.u[1]) : "v"(in.u[1]), "v"(hdup));
  asm("v_pk_mul_f16 %0, %1, %2" : "=v"(out.u[2]) : "v"(in.u[2]), "v"(hdup));
  asm("v_pk_mul_f16 %0, %1, %2" : "=v"(out.u[3]) : "v"(in.u[3]), "v"(hdup));
  return out.v;
}

__device__ __forceinline__ unsigned dup16(float f) {
  f16 h = (f16)f;
  union { f16 h; unsigned short s; } u; u.h = h;
  return (unsigned)u.s * 0x10001u;
}

// ---- pre-pass: scatter W f32 -> f16 fragment-major ----
// Wb slot layout: [c][slot][8], slot = (g*4+kk)*64 + hi*32 + lr
//   holds W[f=g*32+lr][c][kk*16+hi*8 .. +8]
__global__ __launch_bounds__(256) void wscat_kernel(const float* __restrict__ W,
                                                    f16* __restrict__ Wb) {
  const int tid = blockIdx.x * 256 + threadIdx.x;   // 65536 threads
  const int c = tid >> 10, s = tid & 1023;
  const int gk = s >> 6, ln = s & 63;
  const int g = gk >> 2, kk = gk & 3, hi = ln >> 5, lr = ln & 31;
  const int f = g * 32 + lr, n0 = kk * 16 + hi * 8;
  const float* src = W + (size_t)f * 4096 + c * 64 + n0;
  const float4 a = *(const float4*)src;
  const float4 b = *(const float4*)(src + 4);
  half8 r;
  r[0] = (f16)a.x; r[1] = (f16)a.y; r[2] = (f16)a.z; r[3] = (f16)a.w;
  r[4] = (f16)b.x; r[5] = (f16)b.y; r[6] = (f16)b.z; r[7] = (f16)b.w;
  *(half8*)(Wb + (size_t)c * 8192 + s * 8) = r;
}

__global__ __launch_bounds__(256, 2) void cin_kernel(
    const float* __restrict__ xj, const float* __restrict__ x0,
    const f16* __restrict__ Wb, float* __restrict__ out,
    float* __restrict__ pout) {
  // x0T[bb*4096 + d*64 + ((n>>3)^(d&7))*8 + (n&7)] = f16(x0[b0+bb][n][d])
  __shared__ f16 x0T[2 * 4096];        // 16 KB
  // xjD[bb*4096 + c*64 + d] = dup16(xj[b0+bb][c][d])  (u32 broadcast pairs)
  __shared__ unsigned xjD[2 * 4096];   // 32 KB

  const int t = threadIdx.x;
  const int wid = t >> 6, lane = t & 63;
  const int b0 = blockIdx.x * 2;

  // ---- one-time: stage x0 (transposed, swizzled) + xj (dup-u32) ----
#pragma unroll
  for (int bb = 0; bb < 2; ++bb) {
    const float* s0 = x0 + (size_t)(b0 + bb) * 4096;
    const float* sj = xj + (size_t)(b0 + bb) * 4096;
    {
      const int n = lane, d0 = wid * 16;
      const int chb = n >> 3, sub = n & 7;
#pragma unroll
      for (int q = 0; q < 4; ++q) {
        const float4 v = *(const float4*)(s0 + n * 64 + d0 + q * 4);
#pragma unroll
        for (int j = 0; j < 4; ++j) {
          const int d = d0 + q * 4 + j;
          x0T[bb * 4096 + d * 64 + ((chb ^ (d & 7)) << 3) + sub] =
              (f16)(((const float*)&v)[j]);
        }
      }
    }
#pragma unroll
    for (int p = 0; p < 4; ++p) {
      const int e = p * 1024 + t * 4;
      const float4 v = *(const float4*)(sj + e);
      unsigned* dst = &xjD[bb * 4096 + e];
      dst[0] = dup16(v.x); dst[1] = dup16(v.y);
      dst[2] = dup16(v.z); dst[3] = dup16(v.w);
    }
  }
  __syncthreads();

  const int wg = wid;                       // f-group: f = wg*32 + lr
  const int lr = lane & 31, hi = lane >> 5;

  // ---- hoisted x0 A-fragments: af[mf][kk], mf = (bb<<1)|dh ----
  half8 af[4][4];
#pragma unroll
  for (int mf = 0; mf < 4; ++mf) {
    const int bb = mf >> 1;
    const int d = (mf & 1) * 32 + lr;
#pragma unroll
    for (int kk = 0; kk < 4; ++kk)
      af[mf][kk] = *(const half8*)&x0T[bb * 4096 + d * 64 +
                                       (((kk * 2 + hi) ^ (d & 7)) << 3)];
  }

  f32x16 acc[4] = {};

  // W stream: wave wg's slice, 16B/lane contiguous per (c,kk)
  const half8* wp = (const half8*)Wb + wg * 256 + lane;   // + c*1024 + kk*64
  // xj dup-pair LDS bases (u32 elems); offsets {0,32,4096,4128}
  const unsigned* xjA = &xjD[lr];          // even c
  const unsigned* xjB = &xjD[lr] + 64;     // odd c

  // ---- prologue: c=0 -> A sets, c=1 -> B sets ----
  half8 wA0 = wp[0],    wA1 = wp[64],        wA2 = wp[128],        wA3 = wp[192];
  half8 wB0 = wp[1024], wB1 = wp[1024 + 64], wB2 = wp[1024 + 128], wB3 = wp[1024 + 192];
  unsigned xA0 = xjA[0], xA1 = xjA[32], xA2 = xjA[4096], xA3 = xjA[4096 + 32];
  unsigned xB0 = xjB[0], xB1 = xjB[32], xB2 = xjB[4096], xB3 = xjB[4096 + 32];

  // moving prefetch pointers (next targets: c=2 / c=3)
  const half8* wpA = wp + 2048;
  const half8* wpB = wp + 3072;
  const unsigned* xjpA = xjA + 128;
  const unsigned* xjpB = xjB + 128;

#pragma unroll 1
  for (int cc = 0; cc < 32; ++cc) {
    // ================= even c = 2*cc (A sets) =================
    {
      __builtin_amdgcn_s_setprio(1);
#pragma unroll
      for (int kk = 0; kk < 4; ++kk) {
        const half8 w = (kk == 0) ? wA0 : (kk == 1) ? wA1 : (kk == 2) ? wA2 : wA3;
        acc[0] = MFMA(scale8a(af[0][kk], xA0), w, acc[0]);
        acc[1] = MFMA(scale8a(af[1][kk], xA1), w, acc[1]);
        acc[2] = MFMA(scale8a(af[2][kk], xA2), w, acc[2]);
        acc[3] = MFMA(scale8a(af[3][kk], xA3), w, acc[3]);
      }
      __builtin_amdgcn_s_setprio(0);
      if (cc < 31) {
        wA0 = wpA[0]; wA1 = wpA[64]; wA2 = wpA[128]; wA3 = wpA[192];
        xA0 = xjpA[0]; xA1 = xjpA[32]; xA2 = xjpA[4096]; xA3 = xjpA[4096 + 32];
        wpA += 2048; xjpA += 128;
      }
    }
    // ================= odd c = 2*cc+1 (B sets) =================
    {
      __builtin_amdgcn_s_setprio(1);
#pragma unroll
      for (int kk = 0; kk < 4; ++kk) {
        const half8 w = (kk == 0) ? wB0 : (kk == 1) ? wB1 : (kk == 2) ? wB2 : wB3;
        acc[0] = MFMA(scale8a(af[0][kk], xB0), w, acc[0]);
        acc[1] = MFMA(scale8a(af[1][kk], xB1), w, acc[1]);
        acc[2] = MFMA(scale8a(af[2][kk], xB2), w, acc[2]);
        acc[3] = MFMA(scale8a(af[3][kk], xB3), w, acc[3]);
      }
      __builtin_amdgcn_s_setprio(0);
      if (cc < 31) {
        wB0 = wpB[0]; wB1 = wpB[64]; wB2 = wpB[128]; wB3 = wpB[192];
        xB0 = xjpB[0]; xB1 = xjpB[32]; xB2 = xjpB[4096]; xB3 = xjpB[4096 + 32];
        wpB += 2048; xjpB += 128;
      }
    }
  }

  // ---- epilogue: D layout col=lane&31 (f), row=(reg&3)+8*(reg>>2)+4*hi (d) ----
  const int fcol = wg * 32 + lr;
  float ps[4];
#pragma unroll
  for (int mf = 0; mf < 4; ++mf) {
    const int b = b0 + (mf >> 1);
    float* ob = out + (size_t)b * 8192 + (size_t)fcol * 64 + (mf & 1) * 32;
    const f32x16 v = acc[mf];
    float s = 0.f;
#pragma unroll
    for (int q = 0; q < 4; ++q) {
      f32x4 vv = { v[4 * q], v[4 * q + 1], v[4 * q + 2], v[4 * q + 3] };
      *(f32x4*)(ob + q * 8 + hi * 4) = vv;
      s += vv[0] + vv[1] + vv[2] + vv[3];
    }
    ps[mf] = s;
  }
  float pA = ps[0] + ps[1];   // batch b0
  float pB = ps[2] + ps[3];   // batch b0+1
  pA += __shfl_xor(pA, 32, 64);
  pB += __shfl_xor(pB, 32, 64);
  if (hi == 0) {
    pout[(size_t)b0 * 128 + fcol] = pA;
    pout[(size_t)(b0 + 1) * 128 + fcol] = pB;
  }
}

extern "C" void kernel_launch(void* const* d_in, const int* in_sizes, int n_in,
                              void* d_out, int out_size, void* d_ws, size_t ws_size,
                              hipStream_t stream) {
  const float* xj = (const float*)d_in[0];   // (2048, 64, 64)
  const float* x0 = (const float*)d_in[1];   // (2048, 64, 64)
  const float* W  = (const float*)d_in[2];   // (128, 64, 64)
  float* out  = (float*)d_out;               // cin_out (2048,128,64), cin_p_out (2048,128)
  float* pout = out + (size_t)2048 * 128 * 64;
  f16* Wb = (f16*)d_ws;                      // 1 MiB fragment-major f16 W

  wscat_kernel<<<256, 256, 0, stream>>>(W, Wb);
  cin_kernel<<<1024, 256, 0, stream>>>(xj, x0, Wb, out, pout);
}